// Round 5
// baseline (445.703 us; speedup 1.0000x reference)
//
#include <hip/hip_runtime.h>
#include <hip/hip_fp16.h>
#include <math.h>

__device__ __forceinline__ float2 h2f2(unsigned int u) {
    __half2 h = *reinterpret_cast<__half2*>(&u);
    return __half22float2(h);
}
__device__ __forceinline__ unsigned int f2h2(float a, float b) {
    __half2 h = __floats2half2_rn(a, b);
    return *reinterpret_cast<unsigned int*>(&h);
}

// ---------------- STAGGER-FUSED: every block does ONE GEMM tile AND one hist slice ----------------
// Epilogue stores Y fp16 (gather operand downstream). INT atomics only — global fp32
// atomicAdd measured as memory-side 64B RMW (round-3: +99MB WRITE_SIZE, +50us).
__global__ __launch_bounds__(256) void gemm128_hist_kernel(
        const float* __restrict__ X, const float* __restrict__ W, __half* __restrict__ Y, int n,
        const int* __restrict__ dst, int* __restrict__ cnt, int* __restrict__ rank, int E) {
    constexpr int CG  = 32;
    constexpr int M   = 64;
    constexpr int RT  = 8;
    constexpr int KC  = 32;
    constexpr int LDX = 132;
    __shared__ float  Xl[M * LDX];      // 33792 B
    __shared__ float4 Wl[KC * CG];      // 16384 B

    const int bid = blockIdx.x;
    const int t = threadIdx.x;
    const int EPB = (E + (int)gridDim.x - 1) / (int)gridDim.x;
    const int eBeg = bid * EPB;
    const int eEnd = min(eBeg + EPB, E);

    if ((bid & 1) == 0) {
        for (int e = eBeg + t; e < eEnd; e += 256)
            rank[e] = atomicAdd(&cnt[dst[e]], 1);
    }

    int row0 = bid * M;
    {
        const float4* Xg = (const float4*)X;
        for (int f = t; f < M * 32; f += 256) {
            int r = f >> 5, c4 = f & 31;
            int gr = row0 + r;
            float4 v = make_float4(0.f, 0.f, 0.f, 0.f);
            if (gr < n) v = Xg[(size_t)gr * 32 + c4];
            *(float4*)&Xl[r * LDX + c4 * 4] = v;
        }
    }

    int cg = t % CG;
    int r0 = (t / CG) * RT;

    float4 acc[RT];
#pragma unroll
    for (int r = 0; r < RT; r++) acc[r] = make_float4(0.f, 0.f, 0.f, 0.f);

    const float4* Wg = (const float4*)W;
    for (int kc = 0; kc < 128; kc += KC) {
        __syncthreads();
        for (int f = t; f < KC * CG; f += 256)
            Wl[f] = Wg[(size_t)kc * CG + f];
        __syncthreads();
#pragma unroll 4
        for (int k = 0; k < KC; k += 4) {
            float4 b0 = Wl[(k + 0) * CG + cg];
            float4 b1 = Wl[(k + 1) * CG + cg];
            float4 b2 = Wl[(k + 2) * CG + cg];
            float4 b3 = Wl[(k + 3) * CG + cg];
#pragma unroll
            for (int r = 0; r < RT; r++) {
                float4 a = *(float4*)&Xl[(r0 + r) * LDX + kc + k];
                acc[r].x += a.x * b0.x + a.y * b1.x + a.z * b2.x + a.w * b3.x;
                acc[r].y += a.x * b0.y + a.y * b1.y + a.z * b2.y + a.w * b3.y;
                acc[r].z += a.x * b0.z + a.y * b1.z + a.z * b2.z + a.w * b3.z;
                acc[r].w += a.x * b0.w + a.y * b1.w + a.z * b2.w + a.w * b3.w;
            }
        }
    }

#pragma unroll
    for (int r = 0; r < RT; r++) {
        int gr = row0 + r0 + r;
        if (gr < n) {
            uint2 u = make_uint2(f2h2(acc[r].x, acc[r].y), f2h2(acc[r].z, acc[r].w));
            *(uint2*)&Y[(size_t)gr * 128 + cg * 4] = u;
        }
    }

    if (bid & 1) {
        for (int e = eBeg + t; e < eEnd; e += 256)
            rank[e] = atomicAdd(&cnt[dst[e]], 1);
    }
}

// exclusive scan, stage 1
__global__ __launch_bounds__(256) void scan_block(const int* __restrict__ in, int* __restrict__ out,
                                                  int* __restrict__ bsum, int n) {
    __shared__ int s[256];
    int tid = threadIdx.x;
    int base = blockIdx.x * 1024 + tid * 4;
    int a0 = (base + 0 < n) ? in[base + 0] : 0;
    int a1 = (base + 1 < n) ? in[base + 1] : 0;
    int a2 = (base + 2 < n) ? in[base + 2] : 0;
    int a3 = (base + 3 < n) ? in[base + 3] : 0;
    int tsum = a0 + a1 + a2 + a3;
    s[tid] = tsum;
    __syncthreads();
    for (int off = 1; off < 256; off <<= 1) {
        int v = (tid >= off) ? s[tid - off] : 0;
        __syncthreads();
        s[tid] += v;
        __syncthreads();
    }
    int texcl = s[tid] - tsum;
    if (base + 0 < n) out[base + 0] = texcl;
    if (base + 1 < n) out[base + 1] = texcl + a0;
    if (base + 2 < n) out[base + 2] = texcl + a0 + a1;
    if (base + 3 < n) out[base + 3] = texcl + a0 + a1 + a2;
    if (tid == 255) bsum[blockIdx.x] = s[255];
}

// stage 2
__global__ __launch_bounds__(256) void scan_bsums(int* __restrict__ bsum, int nb) {
    __shared__ int s[256];
    __shared__ int carry_s;
    int tid = threadIdx.x;
    if (tid == 0) carry_s = 0;
    __syncthreads();
    for (int base = 0; base < nb; base += 256) {
        int v = (base + tid < nb) ? bsum[base + tid] : 0;
        int orig = v;
        s[tid] = v;
        __syncthreads();
        for (int off = 1; off < 256; off <<= 1) {
            int u = (tid >= off) ? s[tid - off] : 0;
            __syncthreads();
            s[tid] += u;
            __syncthreads();
        }
        int carry = carry_s;
        int excl = s[tid] - orig + carry;
        if (base + tid < nb) bsum[base + tid] = excl;
        int tot = s[255];
        __syncthreads();
        if (tid == 0) carry_s = carry + tot;
        __syncthreads();
    }
}

// stage 3
__global__ void scan_add(int* __restrict__ rowptr, const int* __restrict__ bscan, int n) {
    int t = blockIdx.x * blockDim.x + threadIdx.x;
    if (t < n) rowptr[t] += bscan[t >> 10];
}

// atomic-free CSR placement: pairs hold (src, RAW ew)
__global__ void scatter_pairs(const int* __restrict__ src, const int* __restrict__ dst,
                              const float* __restrict__ ew, const int* __restrict__ rowptr,
                              const int* __restrict__ rank, int2* __restrict__ pairs, int E) {
    int e = blockIdx.x * blockDim.x + threadIdx.x;
    if (e >= E) return;
    int d = dst[e];
    int p = rowptr[d] + rank[e];
    pairs[p] = make_int2(src[e], __float_as_int(ew[e]));
}

// degree from CONTIGUOUS segment sum of sorted RAW ew (no atomics); dinv = 1/sqrt(deg+1)
__global__ void deg_dinv_kernel(const int2* __restrict__ pairs, const int* __restrict__ rowptr,
                                float* __restrict__ dinv, int n) {
    int i = blockIdx.x * blockDim.x + threadIdx.x;
    if (i >= n) return;
    int beg = rowptr[i], end = rowptr[i + 1];
    float s = 0.f;
    for (int j = beg; j < end; j++) s += __int_as_float(pairs[j].y);
    dinv[i] = 1.0f / sqrtf(s + 1.0f);
}

// fold dinv[src] into the edge weight once
__global__ void premul_kernel(int2* __restrict__ pairs, const float* __restrict__ dinv, int E) {
    int e = blockIdx.x * blockDim.x + threadIdx.x;
    if (e >= E) return;
    int2 p = pairs[e];
    p.y = __float_as_int(__int_as_float(p.y) * dinv[p.x]);
    pairs[e] = p;
}

// ---------------- FUSED layer-1 gather + ReLU + matvec h1@W2 ----------------
// 2-deep software pipeline: H-loads for batch k+1 issued BEFORE consuming batch k;
// pairs prefetched 2 batches ahead so H-issue never waits on pairs. Weights extracted
// (and tail-masked) at H-issue time so pairs registers die early. A/B phase unroll
// avoids rotation movs.
__global__ __launch_bounds__(512, 4) void gather_mv_kernel(const __half* __restrict__ H,
                                                           const int* __restrict__ rowptr,
                                                           const int2* __restrict__ pairs,
                                                           const float* __restrict__ dinv,
                                                           const float* __restrict__ bias,
                                                           const float* __restrict__ W2,
                                                           __half* __restrict__ Z, int n) {
    __shared__ float h1s[16 * 128];    // 8 KB
    __shared__ float w2s[128 * 64];    // 32 KB, full W2
    const int t = threadIdx.x;
    const int nl = t >> 5;
    const int c4 = t & 31;
    const int node = blockIdx.x * 16 + nl;

    // stage full W2 (coalesced; L2-hot after first blocks)
    {
        const float4* W2g = (const float4*)W2;
        float4* w2s4 = (float4*)w2s;
#pragma unroll
        for (int f = 0; f < 4; f++) w2s4[f * 512 + t] = W2g[f * 512 + t];
    }

    float4 acc[4];
#pragma unroll
    for (int i = 0; i < 4; i++) acc[i] = make_float4(0.f, 0.f, 0.f, 0.f);

    float di = 0.f;
    int beg = 0, end = 0;
    if (node < n) {
        beg = rowptr[node]; end = rowptr[node + 1];
        di = dinv[node];
        uint2 hv = *(const uint2*)&H[(size_t)node * 128 + c4 * 4];
        float2 f01 = h2f2(hv.x), f23 = h2f2(hv.y);
        acc[0].x = f01.x * di; acc[0].y = f01.y * di;
        acc[0].z = f23.x * di; acc[0].w = f23.y * di;
    }

    const __half* Hc = H + c4 * 4;   // per-lane column base

    if (beg < end) {
        int2 pa[8], pb[8];
        float wa[8], wb[8];
        uint2 va[8], vb[8];
#pragma unroll
        for (int i = 0; i < 8; i++) { int jj = beg + i;     pa[i] = pairs[jj < end ? jj : beg]; }
#pragma unroll
        for (int i = 0; i < 8; i++) { int jj = beg + 8 + i; pb[i] = pairs[jj < end ? jj : beg]; }
#pragma unroll
        for (int i = 0; i < 8; i++) {
            wa[i] = (beg + i < end) ? __int_as_float(pa[i].y) : 0.f;
            va[i] = *(const uint2*)&Hc[(size_t)(unsigned)pa[i].x * 128];
        }
        for (int j = beg; j < end; j += 16) {
            // ---- phase A: issue batch j+8, prefetch pairs j+16, consume batch j ----
#pragma unroll
            for (int i = 0; i < 8; i++) {
                wb[i] = (j + 8 + i < end) ? __int_as_float(pb[i].y) : 0.f;
                vb[i] = *(const uint2*)&Hc[(size_t)(unsigned)pb[i].x * 128];
            }
#pragma unroll
            for (int i = 0; i < 8; i++) { int jj = j + 16 + i; pa[i] = pairs[jj < end ? jj : beg]; }
#pragma unroll
            for (int i = 0; i < 8; i++) {
                float2 g01 = h2f2(va[i].x), g23 = h2f2(va[i].y);
                acc[i & 3].x += g01.x * wa[i]; acc[i & 3].y += g01.y * wa[i];
                acc[i & 3].z += g23.x * wa[i]; acc[i & 3].w += g23.y * wa[i];
            }
            // ---- phase B: issue batch j+16, prefetch pairs j+24, consume batch j+8 ----
#pragma unroll
            for (int i = 0; i < 8; i++) {
                wa[i] = (j + 16 + i < end) ? __int_as_float(pa[i].y) : 0.f;
                va[i] = *(const uint2*)&Hc[(size_t)(unsigned)pa[i].x * 128];
            }
#pragma unroll
            for (int i = 0; i < 8; i++) { int jj = j + 24 + i; pb[i] = pairs[jj < end ? jj : beg]; }
#pragma unroll
            for (int i = 0; i < 8; i++) {
                float2 g01 = h2f2(vb[i].x), g23 = h2f2(vb[i].y);
                acc[i & 3].x += g01.x * wb[i]; acc[i & 3].y += g01.y * wb[i];
                acc[i & 3].z += g23.x * wb[i]; acc[i & 3].w += g23.y * wb[i];
            }
        }
    }

    float4 a0 = make_float4(0.f, 0.f, 0.f, 0.f);
    if (node < n) {
        float4 bb = ((const float4*)bias)[c4];
        a0.x = fmaxf(((acc[0].x + acc[1].x) + (acc[2].x + acc[3].x)) * di + bb.x, 0.f);
        a0.y = fmaxf(((acc[0].y + acc[1].y) + (acc[2].y + acc[3].y)) * di + bb.y, 0.f);
        a0.z = fmaxf(((acc[0].z + acc[1].z) + (acc[2].z + acc[3].z)) * di + bb.z, 0.f);
        a0.w = fmaxf(((acc[0].w + acc[1].w) + (acc[2].w + acc[3].w)) * di + bb.w, 0.f);
    }
    *(float4*)&h1s[nl * 128 + c4 * 4] = a0;
    __syncthreads();   // the ONLY barrier: covers w2s staging + h1s

    // matvec: z[node][2c4], z[node][2c4+1]
    float z0 = 0.f, z1 = 0.f;
    const float* hrow = &h1s[nl * 128];
    const float2* w2c = (const float2*)w2s;   // [128][32] float2
#pragma unroll 8
    for (int k = 0; k < 128; k++) {
        float hk = hrow[k];                   // LDS broadcast within node group
        float2 w = w2c[k * 32 + c4];
        z0 += hk * w.x;
        z1 += hk * w.y;
    }
    if (node < n) *(unsigned int*)&Z[(size_t)node * 64 + c4 * 2] = f2h2(z0, z1);
}

// ---------------- CSR segmented gather-reduce (layer 2, C=64) over fp16 rows ----------------
// Same 2-deep A/B pipeline. 16 lanes/node.
__global__ __launch_bounds__(256, 4) void gather_reduce64(const __half* __restrict__ H,
                                                          const int* __restrict__ rowptr,
                                                          const int2* __restrict__ pairs,
                                                          const float* __restrict__ dinv,
                                                          const float* __restrict__ bias,
                                                          __half* __restrict__ out, int n) {
    constexpr int TPN = 16;
    int t = blockIdx.x * blockDim.x + threadIdx.x;
    int node = t / TPN;
    int c4 = t % TPN;
    if (node >= n) return;
    int beg = rowptr[node], end = rowptr[node + 1];
    float di = dinv[node];
    float4 bb = ((const float4*)bias)[c4];
    float4 acc[4];
    {
        uint2 hv = *(const uint2*)&H[(size_t)node * 64 + c4 * 4];
        float2 f01 = h2f2(hv.x), f23 = h2f2(hv.y);
        acc[0].x = f01.x * di; acc[0].y = f01.y * di;
        acc[0].z = f23.x * di; acc[0].w = f23.y * di;
    }
#pragma unroll
    for (int i = 1; i < 4; i++) acc[i] = make_float4(0.f, 0.f, 0.f, 0.f);

    const __half* Hc = H + c4 * 4;

    if (beg < end) {
        int2 pa[8], pb[8];
        float wa[8], wb[8];
        uint2 va[8], vb[8];
#pragma unroll
        for (int i = 0; i < 8; i++) { int jj = beg + i;     pa[i] = pairs[jj < end ? jj : beg]; }
#pragma unroll
        for (int i = 0; i < 8; i++) { int jj = beg + 8 + i; pb[i] = pairs[jj < end ? jj : beg]; }
#pragma unroll
        for (int i = 0; i < 8; i++) {
            wa[i] = (beg + i < end) ? __int_as_float(pa[i].y) : 0.f;
            va[i] = *(const uint2*)&Hc[(size_t)(unsigned)pa[i].x * 64];
        }
        for (int j = beg; j < end; j += 16) {
            // phase A
#pragma unroll
            for (int i = 0; i < 8; i++) {
                wb[i] = (j + 8 + i < end) ? __int_as_float(pb[i].y) : 0.f;
                vb[i] = *(const uint2*)&Hc[(size_t)(unsigned)pb[i].x * 64];
            }
#pragma unroll
            for (int i = 0; i < 8; i++) { int jj = j + 16 + i; pa[i] = pairs[jj < end ? jj : beg]; }
#pragma unroll
            for (int i = 0; i < 8; i++) {
                float2 g01 = h2f2(va[i].x), g23 = h2f2(va[i].y);
                acc[i & 3].x += g01.x * wa[i]; acc[i & 3].y += g01.y * wa[i];
                acc[i & 3].z += g23.x * wa[i]; acc[i & 3].w += g23.y * wa[i];
            }
            // phase B
#pragma unroll
            for (int i = 0; i < 8; i++) {
                wa[i] = (j + 16 + i < end) ? __int_as_float(pa[i].y) : 0.f;
                va[i] = *(const uint2*)&Hc[(size_t)(unsigned)pa[i].x * 64];
            }
#pragma unroll
            for (int i = 0; i < 8; i++) { int jj = j + 24 + i; pb[i] = pairs[jj < end ? jj : beg]; }
#pragma unroll
            for (int i = 0; i < 8; i++) {
                float2 g01 = h2f2(vb[i].x), g23 = h2f2(vb[i].y);
                acc[i & 3].x += g01.x * wb[i]; acc[i & 3].y += g01.y * wb[i];
                acc[i & 3].z += g23.x * wb[i]; acc[i & 3].w += g23.y * wb[i];
            }
        }
    }

    float4 r;
    r.x = ((acc[0].x + acc[1].x) + (acc[2].x + acc[3].x)) * di + bb.x;
    r.y = ((acc[0].y + acc[1].y) + (acc[2].y + acc[3].y)) * di + bb.y;
    r.z = ((acc[0].z + acc[1].z) + (acc[2].z + acc[3].z)) * di + bb.z;
    r.w = ((acc[0].w + acc[1].w) + (acc[2].w + acc[3].w)) * di + bb.w;
    uint2 u = make_uint2(f2h2(r.x, r.y), f2h2(r.z, r.w));
    *(uint2*)&out[(size_t)node * 64 + c4 * 4] = u;
}

// ---------------- decode (Z fp16) ----------------
__global__ void decode_kernel(const __half* __restrict__ Z, const int* __restrict__ ea,
                              const int* __restrict__ eb, float* __restrict__ out, int L) {
    int t = blockIdx.x * blockDim.x + threadIdx.x;
    int e = t >> 4;
    int c = (t & 15) << 2;
    if (e >= L) return;
    uint2 ua = *(const uint2*)&Z[(size_t)ea[e] * 64 + c];
    uint2 ub = *(const uint2*)&Z[(size_t)eb[e] * 64 + c];
    float2 a01 = h2f2(ua.x), a23 = h2f2(ua.y);
    float2 b01 = h2f2(ub.x), b23 = h2f2(ub.y);
    float p = a01.x * b01.x + a01.y * b01.y + a23.x * b23.x + a23.y * b23.y;
    p += __shfl_xor(p, 1);
    p += __shfl_xor(p, 2);
    p += __shfl_xor(p, 4);
    p += __shfl_xor(p, 8);
    if ((t & 15) == 0) out[e] = p;
}

extern "C" void kernel_launch(void* const* d_in, const int* in_sizes, int n_in,
                              void* d_out, int out_size, void* d_ws, size_t ws_size,
                              hipStream_t stream) {
    const float* x   = (const float*)d_in[0];
    const int*   ei  = (const int*)d_in[1];   // [2,E] flat: src = ei, dst = ei+E
    const float* ew  = (const float*)d_in[2];
    const int*   eli = (const int*)d_in[3];   // [2,L] flat
    const float* W1  = (const float*)d_in[4];
    const float* b1  = (const float*)d_in[5];
    const float* W2  = (const float*)d_in[6];
    const float* b2  = (const float*)d_in[7];
    float* out = (float*)d_out;

    const int N = in_sizes[0] / 128;
    const int E = in_sizes[2];
    const int L = in_sizes[3] / 2;
    const int NP = ((N + 255) / 256) * 256;

    float* ws     = (float*)d_ws;
    float* dinv   = ws;                                  // NP
    int*   cnt    = (int*)(ws + NP);                     // NP (needs N+1, zeroed)
    int*   rowptr = cnt + NP;                            // NP (needs N+1)
    int*   bsum   = rowptr + NP;                         // 1024
    int*   rank   = bsum + 1024;                         // E
    int2*  pairs  = (int2*)(rank + E);                   // E int2
    __half* A     = (__half*)(pairs + E);                // NP*128 halfs (h = x@W1)
    __half* B     = (__half*)((float*)(pairs + E) + (size_t)NP * 128);  // NP*64 halfs
    __half* Zf    = A;                                   // z overwrites A region (A dead by then)

    const int n1 = N + 1;
    const int nb = (n1 + 1023) / 1024;

    hipMemsetAsync(cnt, 0, (size_t)n1 * 4, stream);

    // stagger-fused: layer-1 GEMM tiles + histogram/rank slices (int atomics only)
    const int Gg = (N + 63) / 64;
    gemm128_hist_kernel<<<Gg, 256, 0, stream>>>(x, W1, A, N, ei + E, cnt, rank, E);

    // CSR finish
    scan_block<<<nb, 256, 0, stream>>>(cnt, rowptr, bsum, n1);
    scan_bsums<<<1, 256, 0, stream>>>(bsum, nb);
    scan_add<<<(n1 + 255) / 256, 256, 0, stream>>>(rowptr, bsum, n1);
    scatter_pairs<<<(E + 255) / 256, 256, 0, stream>>>(ei, ei + E, ew, rowptr, rank, pairs, E);
    deg_dinv_kernel<<<(N + 255) / 256, 256, 0, stream>>>(pairs, rowptr, dinv, N);
    premul_kernel<<<(E + 255) / 256, 256, 0, stream>>>(pairs, dinv, E);

    // FUSED: layer-1 aggregate + ReLU + h1@W2  ->  B holds h2' [N,64] fp16
    gather_mv_kernel<<<(N + 15) / 16, 512, 0, stream>>>(A, rowptr, pairs, dinv, b1, W2, B, N);

    // layer-2 aggregate: z = Â h2' + b2  ->  Zf (fp16, overwrites A region)
    gather_reduce64<<<(N * 16 + 255) / 256, 256, 0, stream>>>(B, rowptr, pairs, dinv, b2, Zf, N);

    // decode
    decode_kernel<<<(L * 16 + 255) / 256, 256, 0, stream>>>(Zf, eli, eli + L, out, L);
}

// Round 6
// 443.102 us; speedup vs baseline: 1.0059x; 1.0059x over previous
//
#include <hip/hip_runtime.h>
#include <hip/hip_fp16.h>
#include <math.h>

__device__ __forceinline__ float2 h2f2(unsigned int u) {
    __half2 h = *reinterpret_cast<__half2*>(&u);
    return __half22float2(h);
}
__device__ __forceinline__ unsigned int f2h2(float a, float b) {
    __half2 h = __floats2half2_rn(a, b);
    return *reinterpret_cast<unsigned int*>(&h);
}

// ---------------- STAGGER-FUSED: every block does ONE GEMM tile AND one hist slice ----------------
// Epilogue stores Y fp16 (gather operand downstream). INT atomics only — global fp32
// atomicAdd measured as memory-side 64B RMW (round-3: +99MB WRITE_SIZE, +50us).
__global__ __launch_bounds__(256) void gemm128_hist_kernel(
        const float* __restrict__ X, const float* __restrict__ W, __half* __restrict__ Y, int n,
        const int* __restrict__ dst, int* __restrict__ cnt, int* __restrict__ rank, int E) {
    constexpr int CG  = 32;
    constexpr int M   = 64;
    constexpr int RT  = 8;
    constexpr int KC  = 32;
    constexpr int LDX = 132;
    __shared__ float  Xl[M * LDX];      // 33792 B
    __shared__ float4 Wl[KC * CG];      // 16384 B

    const int bid = blockIdx.x;
    const int t = threadIdx.x;
    const int EPB = (E + (int)gridDim.x - 1) / (int)gridDim.x;
    const int eBeg = bid * EPB;
    const int eEnd = min(eBeg + EPB, E);

    if ((bid & 1) == 0) {
        for (int e = eBeg + t; e < eEnd; e += 256)
            rank[e] = atomicAdd(&cnt[dst[e]], 1);
    }

    int row0 = bid * M;
    {
        const float4* Xg = (const float4*)X;
        for (int f = t; f < M * 32; f += 256) {
            int r = f >> 5, c4 = f & 31;
            int gr = row0 + r;
            float4 v = make_float4(0.f, 0.f, 0.f, 0.f);
            if (gr < n) v = Xg[(size_t)gr * 32 + c4];
            *(float4*)&Xl[r * LDX + c4 * 4] = v;
        }
    }

    int cg = t % CG;
    int r0 = (t / CG) * RT;

    float4 acc[RT];
#pragma unroll
    for (int r = 0; r < RT; r++) acc[r] = make_float4(0.f, 0.f, 0.f, 0.f);

    const float4* Wg = (const float4*)W;
    for (int kc = 0; kc < 128; kc += KC) {
        __syncthreads();
        for (int f = t; f < KC * CG; f += 256)
            Wl[f] = Wg[(size_t)kc * CG + f];
        __syncthreads();
#pragma unroll 4
        for (int k = 0; k < KC; k += 4) {
            float4 b0 = Wl[(k + 0) * CG + cg];
            float4 b1 = Wl[(k + 1) * CG + cg];
            float4 b2 = Wl[(k + 2) * CG + cg];
            float4 b3 = Wl[(k + 3) * CG + cg];
#pragma unroll
            for (int r = 0; r < RT; r++) {
                float4 a = *(float4*)&Xl[(r0 + r) * LDX + kc + k];
                acc[r].x += a.x * b0.x + a.y * b1.x + a.z * b2.x + a.w * b3.x;
                acc[r].y += a.x * b0.y + a.y * b1.y + a.z * b2.y + a.w * b3.y;
                acc[r].z += a.x * b0.z + a.y * b1.z + a.z * b2.z + a.w * b3.z;
                acc[r].w += a.x * b0.w + a.y * b1.w + a.z * b2.w + a.w * b3.w;
            }
        }
    }

#pragma unroll
    for (int r = 0; r < RT; r++) {
        int gr = row0 + r0 + r;
        if (gr < n) {
            uint2 u = make_uint2(f2h2(acc[r].x, acc[r].y), f2h2(acc[r].z, acc[r].w));
            *(uint2*)&Y[(size_t)gr * 128 + cg * 4] = u;
        }
    }

    if (bid & 1) {
        for (int e = eBeg + t; e < eEnd; e += 256)
            rank[e] = atomicAdd(&cnt[dst[e]], 1);
    }
}

// exclusive scan, stage 1
__global__ __launch_bounds__(256) void scan_block(const int* __restrict__ in, int* __restrict__ out,
                                                  int* __restrict__ bsum, int n) {
    __shared__ int s[256];
    int tid = threadIdx.x;
    int base = blockIdx.x * 1024 + tid * 4;
    int a0 = (base + 0 < n) ? in[base + 0] : 0;
    int a1 = (base + 1 < n) ? in[base + 1] : 0;
    int a2 = (base + 2 < n) ? in[base + 2] : 0;
    int a3 = (base + 3 < n) ? in[base + 3] : 0;
    int tsum = a0 + a1 + a2 + a3;
    s[tid] = tsum;
    __syncthreads();
    for (int off = 1; off < 256; off <<= 1) {
        int v = (tid >= off) ? s[tid - off] : 0;
        __syncthreads();
        s[tid] += v;
        __syncthreads();
    }
    int texcl = s[tid] - tsum;
    if (base + 0 < n) out[base + 0] = texcl;
    if (base + 1 < n) out[base + 1] = texcl + a0;
    if (base + 2 < n) out[base + 2] = texcl + a0 + a1;
    if (base + 3 < n) out[base + 3] = texcl + a0 + a1 + a2;
    if (tid == 255) bsum[blockIdx.x] = s[255];
}

// stage 2
__global__ __launch_bounds__(256) void scan_bsums(int* __restrict__ bsum, int nb) {
    __shared__ int s[256];
    __shared__ int carry_s;
    int tid = threadIdx.x;
    if (tid == 0) carry_s = 0;
    __syncthreads();
    for (int base = 0; base < nb; base += 256) {
        int v = (base + tid < nb) ? bsum[base + tid] : 0;
        int orig = v;
        s[tid] = v;
        __syncthreads();
        for (int off = 1; off < 256; off <<= 1) {
            int u = (tid >= off) ? s[tid - off] : 0;
            __syncthreads();
            s[tid] += u;
            __syncthreads();
        }
        int carry = carry_s;
        int excl = s[tid] - orig + carry;
        if (base + tid < nb) bsum[base + tid] = excl;
        int tot = s[255];
        __syncthreads();
        if (tid == 0) carry_s = carry + tot;
        __syncthreads();
    }
}

// stage 3
__global__ void scan_add(int* __restrict__ rowptr, const int* __restrict__ bscan, int n) {
    int t = blockIdx.x * blockDim.x + threadIdx.x;
    if (t < n) rowptr[t] += bscan[t >> 10];
}

// atomic-free CSR placement: pairs hold (src, RAW ew)
__global__ void scatter_pairs(const int* __restrict__ src, const int* __restrict__ dst,
                              const float* __restrict__ ew, const int* __restrict__ rowptr,
                              const int* __restrict__ rank, int2* __restrict__ pairs, int E) {
    int e = blockIdx.x * blockDim.x + threadIdx.x;
    if (e >= E) return;
    int d = dst[e];
    int p = rowptr[d] + rank[e];
    pairs[p] = make_int2(src[e], __float_as_int(ew[e]));
}

// degree from CONTIGUOUS segment sum of sorted RAW ew (no atomics); dinv = 1/sqrt(deg+1)
__global__ void deg_dinv_kernel(const int2* __restrict__ pairs, const int* __restrict__ rowptr,
                                float* __restrict__ dinv, int n) {
    int i = blockIdx.x * blockDim.x + threadIdx.x;
    if (i >= n) return;
    int beg = rowptr[i], end = rowptr[i + 1];
    float s = 0.f;
    for (int j = beg; j < end; j++) s += __int_as_float(pairs[j].y);
    dinv[i] = 1.0f / sqrtf(s + 1.0f);
}

// fold dinv[src] into the edge weight once
__global__ void premul_kernel(int2* __restrict__ pairs, const float* __restrict__ dinv, int E) {
    int e = blockIdx.x * blockDim.x + threadIdx.x;
    if (e >= E) return;
    int2 p = pairs[e];
    p.y = __float_as_int(__int_as_float(p.y) * dinv[p.x]);
    pairs[e] = p;
}

// ---------------- FUSED layer-1 gather + ReLU + matvec h1@W2 ----------------
// Pairs via per-lane load + __shfl broadcast (ds_bpermute -> lgkmcnt): H-load addresses
// depend only on registers, so H loads pipeline with rolling in-order vmcnt(8) waits and
// NO full drains (round-5 lesson: just-in-time global pairs loads force vmcnt(0) drains).
// One coalesced pairs load per 32-edge chunk; weights tail-masked at shfl time.
__global__ __launch_bounds__(512, 4) void gather_mv_kernel(const __half* __restrict__ H,
                                                           const int* __restrict__ rowptr,
                                                           const int2* __restrict__ pairs,
                                                           const float* __restrict__ dinv,
                                                           const float* __restrict__ bias,
                                                           const float* __restrict__ W2,
                                                           __half* __restrict__ Z, int n) {
    __shared__ float h1s[16 * 128];    // 8 KB
    __shared__ float w2s[128 * 64];    // 32 KB, full W2
    const int t = threadIdx.x;
    const int nl = t >> 5;
    const int c4 = t & 31;
    const int node = blockIdx.x * 16 + nl;

    // stage full W2 (coalesced; L2-hot after first blocks)
    {
        const float4* W2g = (const float4*)W2;
        float4* w2s4 = (float4*)w2s;
#pragma unroll
        for (int f = 0; f < 4; f++) w2s4[f * 512 + t] = W2g[f * 512 + t];
    }

    float4 acc[4];
#pragma unroll
    for (int i = 0; i < 4; i++) acc[i] = make_float4(0.f, 0.f, 0.f, 0.f);

    float di = 0.f;
    int beg = 0, end = 0;
    if (node < n) {
        beg = rowptr[node]; end = rowptr[node + 1];
        di = dinv[node];
        uint2 hv = *(const uint2*)&H[(size_t)node * 128 + c4 * 4];
        float2 f01 = h2f2(hv.x), f23 = h2f2(hv.y);
        acc[0].x = f01.x * di; acc[0].y = f01.y * di;
        acc[0].z = f23.x * di; acc[0].w = f23.y * di;
    }

    const __half* Hc = H + c4 * 4;   // per-lane column base
    const int lane = t & 31;
    const int sb = t & 32;           // wave-relative group base for shfl

    for (int base = beg; base < end; base += 32) {
        int idx = base + lane;
        int2 pe = pairs[idx < end ? idx : beg];   // ONE coalesced load per 32-edge chunk
        int m = end - base; if (m > 32) m = 32;
        uint2 vA[8], vB[8];
        float wA[8], wB[8];
        // batch 0 -> A
#pragma unroll
        for (int i = 0; i < 8; i++) {
            int s = __shfl(pe.x, sb + i, 64);
            int w = __shfl(pe.y, sb + i, 64);
            wA[i] = (i < m) ? __int_as_float(w) : 0.f;
            vA[i] = *(const uint2*)&Hc[(size_t)(unsigned)s * 128];
        }
        // batch 1 -> B
        if (m > 8) {
#pragma unroll
            for (int i = 0; i < 8; i++) {
                int s = __shfl(pe.x, sb + 8 + i, 64);
                int w = __shfl(pe.y, sb + 8 + i, 64);
                wB[i] = (8 + i < m) ? __int_as_float(w) : 0.f;
                vB[i] = *(const uint2*)&Hc[(size_t)(unsigned)s * 128];
            }
        }
        // consume A (vmcnt(8): only B outstanding)
#pragma unroll
        for (int i = 0; i < 8; i++) {
            float2 g01 = h2f2(vA[i].x), g23 = h2f2(vA[i].y);
            acc[i & 3].x += g01.x * wA[i]; acc[i & 3].y += g01.y * wA[i];
            acc[i & 3].z += g23.x * wA[i]; acc[i & 3].w += g23.y * wA[i];
        }
        // refill A with batch 2
        if (m > 16) {
#pragma unroll
            for (int i = 0; i < 8; i++) {
                int s = __shfl(pe.x, sb + 16 + i, 64);
                int w = __shfl(pe.y, sb + 16 + i, 64);
                wA[i] = (16 + i < m) ? __int_as_float(w) : 0.f;
                vA[i] = *(const uint2*)&Hc[(size_t)(unsigned)s * 128];
            }
        }
        // consume B
        if (m > 8) {
#pragma unroll
            for (int i = 0; i < 8; i++) {
                float2 g01 = h2f2(vB[i].x), g23 = h2f2(vB[i].y);
                acc[i & 3].x += g01.x * wB[i]; acc[i & 3].y += g01.y * wB[i];
                acc[i & 3].z += g23.x * wB[i]; acc[i & 3].w += g23.y * wB[i];
            }
        }
        // refill B with batch 3
        if (m > 24) {
#pragma unroll
            for (int i = 0; i < 8; i++) {
                int s = __shfl(pe.x, sb + 24 + i, 64);
                int w = __shfl(pe.y, sb + 24 + i, 64);
                wB[i] = (24 + i < m) ? __int_as_float(w) : 0.f;
                vB[i] = *(const uint2*)&Hc[(size_t)(unsigned)s * 128];
            }
        }
        // consume A (batch 2)
        if (m > 16) {
#pragma unroll
            for (int i = 0; i < 8; i++) {
                float2 g01 = h2f2(vA[i].x), g23 = h2f2(vA[i].y);
                acc[i & 3].x += g01.x * wA[i]; acc[i & 3].y += g01.y * wA[i];
                acc[i & 3].z += g23.x * wA[i]; acc[i & 3].w += g23.y * wA[i];
            }
        }
        // consume B (batch 3)
        if (m > 24) {
#pragma unroll
            for (int i = 0; i < 8; i++) {
                float2 g01 = h2f2(vB[i].x), g23 = h2f2(vB[i].y);
                acc[i & 3].x += g01.x * wB[i]; acc[i & 3].y += g01.y * wB[i];
                acc[i & 3].z += g23.x * wB[i]; acc[i & 3].w += g23.y * wB[i];
            }
        }
    }

    float4 a0 = make_float4(0.f, 0.f, 0.f, 0.f);
    if (node < n) {
        float4 bb = ((const float4*)bias)[c4];
        a0.x = fmaxf(((acc[0].x + acc[1].x) + (acc[2].x + acc[3].x)) * di + bb.x, 0.f);
        a0.y = fmaxf(((acc[0].y + acc[1].y) + (acc[2].y + acc[3].y)) * di + bb.y, 0.f);
        a0.z = fmaxf(((acc[0].z + acc[1].z) + (acc[2].z + acc[3].z)) * di + bb.z, 0.f);
        a0.w = fmaxf(((acc[0].w + acc[1].w) + (acc[2].w + acc[3].w)) * di + bb.w, 0.f);
    }
    *(float4*)&h1s[nl * 128 + c4 * 4] = a0;
    __syncthreads();   // the ONLY barrier: covers w2s staging + h1s

    // matvec: z[node][2c4], z[node][2c4+1]
    float z0 = 0.f, z1 = 0.f;
    const float* hrow = &h1s[nl * 128];
    const float2* w2c = (const float2*)w2s;   // [128][32] float2
#pragma unroll 8
    for (int k = 0; k < 128; k++) {
        float hk = hrow[k];                   // LDS broadcast within node group
        float2 w = w2c[k * 32 + c4];
        z0 += hk * w.x;
        z1 += hk * w.y;
    }
    if (node < n) *(unsigned int*)&Z[(size_t)node * 64 + c4 * 2] = f2h2(z0, z1);
}

// ---------------- CSR segmented gather-reduce (layer 2, C=64) over fp16 rows ----------------
// Same shfl-pairs pipeline; 16 lanes/node, 32-edge chunks via two per-lane pairs loads.
__global__ __launch_bounds__(256, 4) void gather_reduce64(const __half* __restrict__ H,
                                                          const int* __restrict__ rowptr,
                                                          const int2* __restrict__ pairs,
                                                          const float* __restrict__ dinv,
                                                          const float* __restrict__ bias,
                                                          __half* __restrict__ out, int n) {
    constexpr int TPN = 16;
    int t = blockIdx.x * blockDim.x + threadIdx.x;
    int node = t / TPN;
    int c4 = t % TPN;
    if (node >= n) return;
    int beg = rowptr[node], end = rowptr[node + 1];
    float di = dinv[node];
    float4 bb = ((const float4*)bias)[c4];
    float4 acc[4];
    {
        uint2 hv = *(const uint2*)&H[(size_t)node * 64 + c4 * 4];
        float2 f01 = h2f2(hv.x), f23 = h2f2(hv.y);
        acc[0].x = f01.x * di; acc[0].y = f01.y * di;
        acc[0].z = f23.x * di; acc[0].w = f23.y * di;
    }
#pragma unroll
    for (int i = 1; i < 4; i++) acc[i] = make_float4(0.f, 0.f, 0.f, 0.f);

    const __half* Hc = H + c4 * 4;
    const int lane = threadIdx.x & 15;
    const int sb = threadIdx.x & 48;   // wave-relative 16-lane group base

    for (int base = beg; base < end; base += 32) {
        int iA = base + lane;
        int iB = base + 16 + lane;
        int2 peA = pairs[iA < end ? iA : beg];          // edges base..base+15
        int2 peB = pairs[iB < end ? iB : beg];          // edges base+16..base+31
        int m = end - base; if (m > 32) m = 32;
        uint2 vA[8], vB[8];
        float wA[8], wB[8];
        // batch 0 -> A (edges 0..7, from peA lanes 0..7)
#pragma unroll
        for (int i = 0; i < 8; i++) {
            int s = __shfl(peA.x, sb + i, 64);
            int w = __shfl(peA.y, sb + i, 64);
            wA[i] = (i < m) ? __int_as_float(w) : 0.f;
            vA[i] = *(const uint2*)&Hc[(size_t)(unsigned)s * 64];
        }
        // batch 1 -> B (edges 8..15, peA lanes 8..15)
        if (m > 8) {
#pragma unroll
            for (int i = 0; i < 8; i++) {
                int s = __shfl(peA.x, sb + 8 + i, 64);
                int w = __shfl(peA.y, sb + 8 + i, 64);
                wB[i] = (8 + i < m) ? __int_as_float(w) : 0.f;
                vB[i] = *(const uint2*)&Hc[(size_t)(unsigned)s * 64];
            }
        }
        // consume A
#pragma unroll
        for (int i = 0; i < 8; i++) {
            float2 g01 = h2f2(vA[i].x), g23 = h2f2(vA[i].y);
            acc[i & 3].x += g01.x * wA[i]; acc[i & 3].y += g01.y * wA[i];
            acc[i & 3].z += g23.x * wA[i]; acc[i & 3].w += g23.y * wA[i];
        }
        // refill A (edges 16..23, peB lanes 0..7)
        if (m > 16) {
#pragma unroll
            for (int i = 0; i < 8; i++) {
                int s = __shfl(peB.x, sb + i, 64);
                int w = __shfl(peB.y, sb + i, 64);
                wA[i] = (16 + i < m) ? __int_as_float(w) : 0.f;
                vA[i] = *(const uint2*)&Hc[(size_t)(unsigned)s * 64];
            }
        }
        // consume B
        if (m > 8) {
#pragma unroll
            for (int i = 0; i < 8; i++) {
                float2 g01 = h2f2(vB[i].x), g23 = h2f2(vB[i].y);
                acc[i & 3].x += g01.x * wB[i]; acc[i & 3].y += g01.y * wB[i];
                acc[i & 3].z += g23.x * wB[i]; acc[i & 3].w += g23.y * wB[i];
            }
        }
        // refill B (edges 24..31, peB lanes 8..15)
        if (m > 24) {
#pragma unroll
            for (int i = 0; i < 8; i++) {
                int s = __shfl(peB.x, sb + 8 + i, 64);
                int w = __shfl(peB.y, sb + 8 + i, 64);
                wB[i] = (24 + i < m) ? __int_as_float(w) : 0.f;
                vB[i] = *(const uint2*)&Hc[(size_t)(unsigned)s * 64];
            }
        }
        // consume A (batch 2)
        if (m > 16) {
#pragma unroll
            for (int i = 0; i < 8; i++) {
                float2 g01 = h2f2(vA[i].x), g23 = h2f2(vA[i].y);
                acc[i & 3].x += g01.x * wA[i]; acc[i & 3].y += g01.y * wA[i];
                acc[i & 3].z += g23.x * wA[i]; acc[i & 3].w += g23.y * wA[i];
            }
        }
        // consume B (batch 3)
        if (m > 24) {
#pragma unroll
            for (int i = 0; i < 8; i++) {
                float2 g01 = h2f2(vB[i].x), g23 = h2f2(vB[i].y);
                acc[i & 3].x += g01.x * wB[i]; acc[i & 3].y += g01.y * wB[i];
                acc[i & 3].z += g23.x * wB[i]; acc[i & 3].w += g23.y * wB[i];
            }
        }
    }

    float4 r;
    r.x = ((acc[0].x + acc[1].x) + (acc[2].x + acc[3].x)) * di + bb.x;
    r.y = ((acc[0].y + acc[1].y) + (acc[2].y + acc[3].y)) * di + bb.y;
    r.z = ((acc[0].z + acc[1].z) + (acc[2].z + acc[3].z)) * di + bb.z;
    r.w = ((acc[0].w + acc[1].w) + (acc[2].w + acc[3].w)) * di + bb.w;
    uint2 u = make_uint2(f2h2(r.x, r.y), f2h2(r.z, r.w));
    *(uint2*)&out[(size_t)node * 64 + c4 * 4] = u;
}

// ---------------- decode (Z fp16) ----------------
__global__ void decode_kernel(const __half* __restrict__ Z, const int* __restrict__ ea,
                              const int* __restrict__ eb, float* __restrict__ out, int L) {
    int t = blockIdx.x * blockDim.x + threadIdx.x;
    int e = t >> 4;
    int c = (t & 15) << 2;
    if (e >= L) return;
    uint2 ua = *(const uint2*)&Z[(size_t)ea[e] * 64 + c];
    uint2 ub = *(const uint2*)&Z[(size_t)eb[e] * 64 + c];
    float2 a01 = h2f2(ua.x), a23 = h2f2(ua.y);
    float2 b01 = h2f2(ub.x), b23 = h2f2(ub.y);
    float p = a01.x * b01.x + a01.y * b01.y + a23.x * b23.x + a23.y * b23.y;
    p += __shfl_xor(p, 1);
    p += __shfl_xor(p, 2);
    p += __shfl_xor(p, 4);
    p += __shfl_xor(p, 8);
    if ((t & 15) == 0) out[e] = p;
}

extern "C" void kernel_launch(void* const* d_in, const int* in_sizes, int n_in,
                              void* d_out, int out_size, void* d_ws, size_t ws_size,
                              hipStream_t stream) {
    const float* x   = (const float*)d_in[0];
    const int*   ei  = (const int*)d_in[1];   // [2,E] flat: src = ei, dst = ei+E
    const float* ew  = (const float*)d_in[2];
    const int*   eli = (const int*)d_in[3];   // [2,L] flat
    const float* W1  = (const float*)d_in[4];
    const float* b1  = (const float*)d_in[5];
    const float* W2  = (const float*)d_in[6];
    const float* b2  = (const float*)d_in[7];
    float* out = (float*)d_out;

    const int N = in_sizes[0] / 128;
    const int E = in_sizes[2];
    const int L = in_sizes[3] / 2;
    const int NP = ((N + 255) / 256) * 256;

    float* ws     = (float*)d_ws;
    float* dinv   = ws;                                  // NP
    int*   cnt    = (int*)(ws + NP);                     // NP (needs N+1, zeroed)
    int*   rowptr = cnt + NP;                            // NP (needs N+1)
    int*   bsum   = rowptr + NP;                         // 1024
    int*   rank   = bsum + 1024;                         // E
    int2*  pairs  = (int2*)(rank + E);                   // E int2
    __half* A     = (__half*)(pairs + E);                // NP*128 halfs (h = x@W1)
    __half* B     = (__half*)((float*)(pairs + E) + (size_t)NP * 128);  // NP*64 halfs
    __half* Zf    = A;                                   // z overwrites A region (A dead by then)

    const int n1 = N + 1;
    const int nb = (n1 + 1023) / 1024;

    hipMemsetAsync(cnt, 0, (size_t)n1 * 4, stream);

    // stagger-fused: layer-1 GEMM tiles + histogram/rank slices (int atomics only)
    const int Gg = (N + 63) / 64;
    gemm128_hist_kernel<<<Gg, 256, 0, stream>>>(x, W1, A, N, ei + E, cnt, rank, E);

    // CSR finish
    scan_block<<<nb, 256, 0, stream>>>(cnt, rowptr, bsum, n1);
    scan_bsums<<<1, 256, 0, stream>>>(bsum, nb);
    scan_add<<<(n1 + 255) / 256, 256, 0, stream>>>(rowptr, bsum, n1);
    scatter_pairs<<<(E + 255) / 256, 256, 0, stream>>>(ei, ei + E, ew, rowptr, rank, pairs, E);
    deg_dinv_kernel<<<(N + 255) / 256, 256, 0, stream>>>(pairs, rowptr, dinv, N);
    premul_kernel<<<(E + 255) / 256, 256, 0, stream>>>(pairs, dinv, E);

    // FUSED: layer-1 aggregate + ReLU + h1@W2  ->  B holds h2' [N,64] fp16
    gather_mv_kernel<<<(N + 15) / 16, 512, 0, stream>>>(A, rowptr, pairs, dinv, b1, W2, B, N);

    // layer-2 aggregate: z = Â h2' + b2  ->  Zf (fp16, overwrites A region)
    gather_reduce64<<<(N * 16 + 255) / 256, 256, 0, stream>>>(B, rowptr, pairs, dinv, b2, Zf, N);

    // decode
    decode_kernel<<<(L * 16 + 255) / 256, 256, 0, stream>>>(Zf, eli, eli + L, out, L);
}

// Round 7
// 406.010 us; speedup vs baseline: 1.0978x; 1.0914x over previous
//
#include <hip/hip_runtime.h>
#include <hip/hip_fp16.h>
#include <math.h>

typedef _Float16 f16x2 __attribute__((ext_vector_type(2)));

__device__ __forceinline__ f16x2 u2h(unsigned int u) { return __builtin_bit_cast(f16x2, u); }
__device__ __forceinline__ unsigned int f2h2(float a, float b) {
    __half2 h = __floats2half2_rn(a, b);
    return *reinterpret_cast<unsigned int*>(&h);
}
__device__ __forceinline__ float fdot2h(unsigned int a, unsigned int b, float c) {
    return __builtin_amdgcn_fdot2(u2h(a), u2h(b), c, false);
}

// ---------------- STAGGER-FUSED: every block does ONE GEMM tile AND one hist slice ----------------
// Epilogue stores Y fp16 (gather operand downstream). INT atomics only — global fp32
// atomicAdd measured as memory-side 64B RMW (round-3: +99MB WRITE_SIZE, +50us).
__global__ __launch_bounds__(256) void gemm128_hist_kernel(
        const float* __restrict__ X, const float* __restrict__ W, __half* __restrict__ Y, int n,
        const int* __restrict__ dst, int* __restrict__ cnt, int* __restrict__ rank, int E) {
    constexpr int CG  = 32;
    constexpr int M   = 64;
    constexpr int RT  = 8;
    constexpr int KC  = 32;
    constexpr int LDX = 132;
    __shared__ float  Xl[M * LDX];      // 33792 B
    __shared__ float4 Wl[KC * CG];      // 16384 B

    const int bid = blockIdx.x;
    const int t = threadIdx.x;
    const int EPB = (E + (int)gridDim.x - 1) / (int)gridDim.x;
    const int eBeg = bid * EPB;
    const int eEnd = min(eBeg + EPB, E);

    if ((bid & 1) == 0) {
        for (int e = eBeg + t; e < eEnd; e += 256)
            rank[e] = atomicAdd(&cnt[dst[e]], 1);
    }

    int row0 = bid * M;
    {
        const float4* Xg = (const float4*)X;
        for (int f = t; f < M * 32; f += 256) {
            int r = f >> 5, c4 = f & 31;
            int gr = row0 + r;
            float4 v = make_float4(0.f, 0.f, 0.f, 0.f);
            if (gr < n) v = Xg[(size_t)gr * 32 + c4];
            *(float4*)&Xl[r * LDX + c4 * 4] = v;
        }
    }

    int cg = t % CG;
    int r0 = (t / CG) * RT;

    float4 acc[RT];
#pragma unroll
    for (int r = 0; r < RT; r++) acc[r] = make_float4(0.f, 0.f, 0.f, 0.f);

    const float4* Wg = (const float4*)W;
    for (int kc = 0; kc < 128; kc += KC) {
        __syncthreads();
        for (int f = t; f < KC * CG; f += 256)
            Wl[f] = Wg[(size_t)kc * CG + f];
        __syncthreads();
#pragma unroll 4
        for (int k = 0; k < KC; k += 4) {
            float4 b0 = Wl[(k + 0) * CG + cg];
            float4 b1 = Wl[(k + 1) * CG + cg];
            float4 b2 = Wl[(k + 2) * CG + cg];
            float4 b3 = Wl[(k + 3) * CG + cg];
#pragma unroll
            for (int r = 0; r < RT; r++) {
                float4 a = *(float4*)&Xl[(r0 + r) * LDX + kc + k];
                acc[r].x += a.x * b0.x + a.y * b1.x + a.z * b2.x + a.w * b3.x;
                acc[r].y += a.x * b0.y + a.y * b1.y + a.z * b2.y + a.w * b3.y;
                acc[r].z += a.x * b0.z + a.y * b1.z + a.z * b2.z + a.w * b3.z;
                acc[r].w += a.x * b0.w + a.y * b1.w + a.z * b2.w + a.w * b3.w;
            }
        }
    }

#pragma unroll
    for (int r = 0; r < RT; r++) {
        int gr = row0 + r0 + r;
        if (gr < n) {
            uint2 u = make_uint2(f2h2(acc[r].x, acc[r].y), f2h2(acc[r].z, acc[r].w));
            *(uint2*)&Y[(size_t)gr * 128 + cg * 4] = u;
        }
    }

    if (bid & 1) {
        for (int e = eBeg + t; e < eEnd; e += 256)
            rank[e] = atomicAdd(&cnt[dst[e]], 1);
    }
}

// exclusive scan, stage 1
__global__ __launch_bounds__(256) void scan_block(const int* __restrict__ in, int* __restrict__ out,
                                                  int* __restrict__ bsum, int n) {
    __shared__ int s[256];
    int tid = threadIdx.x;
    int base = blockIdx.x * 1024 + tid * 4;
    int a0 = (base + 0 < n) ? in[base + 0] : 0;
    int a1 = (base + 1 < n) ? in[base + 1] : 0;
    int a2 = (base + 2 < n) ? in[base + 2] : 0;
    int a3 = (base + 3 < n) ? in[base + 3] : 0;
    int tsum = a0 + a1 + a2 + a3;
    s[tid] = tsum;
    __syncthreads();
    for (int off = 1; off < 256; off <<= 1) {
        int v = (tid >= off) ? s[tid - off] : 0;
        __syncthreads();
        s[tid] += v;
        __syncthreads();
    }
    int texcl = s[tid] - tsum;
    if (base + 0 < n) out[base + 0] = texcl;
    if (base + 1 < n) out[base + 1] = texcl + a0;
    if (base + 2 < n) out[base + 2] = texcl + a0 + a1;
    if (base + 3 < n) out[base + 3] = texcl + a0 + a1 + a2;
    if (tid == 255) bsum[blockIdx.x] = s[255];
}

// stage 2
__global__ __launch_bounds__(256) void scan_bsums(int* __restrict__ bsum, int nb) {
    __shared__ int s[256];
    __shared__ int carry_s;
    int tid = threadIdx.x;
    if (tid == 0) carry_s = 0;
    __syncthreads();
    for (int base = 0; base < nb; base += 256) {
        int v = (base + tid < nb) ? bsum[base + tid] : 0;
        int orig = v;
        s[tid] = v;
        __syncthreads();
        for (int off = 1; off < 256; off <<= 1) {
            int u = (tid >= off) ? s[tid - off] : 0;
            __syncthreads();
            s[tid] += u;
            __syncthreads();
        }
        int carry = carry_s;
        int excl = s[tid] - orig + carry;
        if (base + tid < nb) bsum[base + tid] = excl;
        int tot = s[255];
        __syncthreads();
        if (tid == 0) carry_s = carry + tot;
        __syncthreads();
    }
}

// stage 3
__global__ void scan_add(int* __restrict__ rowptr, const int* __restrict__ bscan, int n) {
    int t = blockIdx.x * blockDim.x + threadIdx.x;
    if (t < n) rowptr[t] += bscan[t >> 10];
}

// atomic-free CSR placement: pairs hold (src, RAW ew)
__global__ void scatter_pairs(const int* __restrict__ src, const int* __restrict__ dst,
                              const float* __restrict__ ew, const int* __restrict__ rowptr,
                              const int* __restrict__ rank, int2* __restrict__ pairs, int E) {
    int e = blockIdx.x * blockDim.x + threadIdx.x;
    if (e >= E) return;
    int d = dst[e];
    int p = rowptr[d] + rank[e];
    pairs[p] = make_int2(src[e], __float_as_int(ew[e]));
}

// degree from CONTIGUOUS segment sum of sorted RAW ew (no atomics); dinv = 1/sqrt(deg+1)
__global__ void deg_dinv_kernel(const int2* __restrict__ pairs, const int* __restrict__ rowptr,
                                float* __restrict__ dinv, int n) {
    int i = blockIdx.x * blockDim.x + threadIdx.x;
    if (i >= n) return;
    int beg = rowptr[i], end = rowptr[i + 1];
    float s = 0.f;
    for (int j = beg; j < end; j++) s += __int_as_float(pairs[j].y);
    dinv[i] = 1.0f / sqrtf(s + 1.0f);
}

// fold dinv[src] into the edge weight once
__global__ void premul_kernel(int2* __restrict__ pairs, const float* __restrict__ dinv, int E) {
    int e = blockIdx.x * blockDim.x + threadIdx.x;
    if (e >= E) return;
    int2 p = pairs[e];
    p.y = __float_as_int(__int_as_float(p.y) * dinv[p.x]);
    pairs[e] = p;
}

// ---------------- FUSED layer-1 gather + ReLU + matvec h1@W2 ----------------
// Round-4 control flow (clamped 8-edge batches + 1-ahead pairs prefetch) — R5/R6 deep
// pipelines both regressed (vmcnt drains / scratch spills). This round: instruction diet.
// fma_mix (fpext fused into fma), 32-bit saddr offsets, dot2 matvec over packed-half2 W2.
__global__ __launch_bounds__(512, 4) void gather_mv_kernel(const __half* __restrict__ H,
                                                           const int* __restrict__ rowptr,
                                                           const int2* __restrict__ pairs,
                                                           const float* __restrict__ dinv,
                                                           const float* __restrict__ bias,
                                                           const float* __restrict__ W2,
                                                           __half* __restrict__ Z, int n) {
    __shared__ unsigned h1s2[16 * 64];   // 4 KB   (h1 rows as half2)
    __shared__ unsigned w2p[64 * 64];    // 16 KB  (W2 packed: (k,k+1) half2 per col)
    const int t = threadIdx.x;
    const int nl = t >> 5;
    const int c4 = t & 31;
    const int node = blockIdx.x * 16 + nl;
    const unsigned coff = (unsigned)c4 * 8u;   // byte offset of this lane's 4 channels

    // stage packed W2: w2p[kp*64 + c] = half2(W2[2kp][c], W2[2kp+1][c])
    {
#pragma unroll
        for (int f = 0; f < 8; f++) {
            int idx = f * 512 + t;
            int kp = idx >> 6, c = idx & 63;
            w2p[idx] = f2h2(W2[(2 * kp) * 64 + c], W2[(2 * kp + 1) * 64 + c]);
        }
    }

    float4 acc[4];
#pragma unroll
    for (int i = 0; i < 4; i++) acc[i] = make_float4(0.f, 0.f, 0.f, 0.f);

    float di = 0.f;
    int beg = 0, end = 0;
    if (node < n) {
        beg = rowptr[node]; end = rowptr[node + 1];
        di = dinv[node];
        uint2 hv = *(const uint2*)((const char*)H + (size_t)(((unsigned)node << 8) + coff));
        f16x2 ha = u2h(hv.x), hb = u2h(hv.y);
        acc[0].x = (float)ha.x * di; acc[0].y = (float)ha.y * di;
        acc[0].z = (float)hb.x * di; acc[0].w = (float)hb.y * di;
    }

    if (beg < end) {
        int2 pc[8];
#pragma unroll
        for (int i = 0; i < 8; i++) {
            int jj = beg + i;
            pc[i] = pairs[jj < end ? jj : beg];
        }
        for (int j = beg; j < end; j += 8) {
            // issue H loads for current batch (independent; saddr form: base H + 32-bit offset)
            uint2 v[8];
#pragma unroll
            for (int i = 0; i < 8; i++)
                v[i] = *(const uint2*)((const char*)H + (size_t)(((unsigned)pc[i].x << 8) + coff));
            // prefetch next pairs batch (clamped; consumed next iteration)
            int2 pn[8];
            int jn = j + 8;
#pragma unroll
            for (int i = 0; i < 8; i++) {
                int jj = jn + i;
                pn[i] = pairs[jj < end ? jj : beg];
            }
            // consume current batch (masked weights for clamped slots); v_fma_mix bodies
#pragma unroll
            for (int i = 0; i < 8; i++) {
                float w = (j + i < end) ? __int_as_float(pc[i].y) : 0.f;
                f16x2 ga = u2h(v[i].x), gb = u2h(v[i].y);
                acc[i & 3].x = fmaf((float)ga.x, w, acc[i & 3].x);
                acc[i & 3].y = fmaf((float)ga.y, w, acc[i & 3].y);
                acc[i & 3].z = fmaf((float)gb.x, w, acc[i & 3].z);
                acc[i & 3].w = fmaf((float)gb.y, w, acc[i & 3].w);
            }
#pragma unroll
            for (int i = 0; i < 8; i++) pc[i] = pn[i];
        }
    }

    // relu + bias in fp32, pack h1 to half2 (h1 is stored fp16 downstream anyway)
    {
        float4 a0 = make_float4(0.f, 0.f, 0.f, 0.f);
        if (node < n) {
            float4 bb = ((const float4*)bias)[c4];
            a0.x = fmaxf(((acc[0].x + acc[1].x) + (acc[2].x + acc[3].x)) * di + bb.x, 0.f);
            a0.y = fmaxf(((acc[0].y + acc[1].y) + (acc[2].y + acc[3].y)) * di + bb.y, 0.f);
            a0.z = fmaxf(((acc[0].z + acc[1].z) + (acc[2].z + acc[3].z)) * di + bb.z, 0.f);
            a0.w = fmaxf(((acc[0].w + acc[1].w) + (acc[2].w + acc[3].w)) * di + bb.w, 0.f);
        }
        h1s2[nl * 64 + c4 * 2 + 0] = f2h2(a0.x, a0.y);
        h1s2[nl * 64 + c4 * 2 + 1] = f2h2(a0.z, a0.w);
    }
    __syncthreads();   // the ONLY barrier: covers w2p staging + h1s2

    // matvec via v_dot2_f32_f16: z[node][2c4], z[node][2c4+1]
    float z0 = 0.f, z1 = 0.f;
    const unsigned* hrow = &h1s2[nl * 64];
#pragma unroll 8
    for (int kp = 0; kp < 64; kp++) {
        unsigned h = hrow[kp];                       // LDS broadcast within node group
        uint2 wv = *(const uint2*)&w2p[kp * 64 + c4 * 2];
        z0 = fdot2h(h, wv.x, z0);
        z1 = fdot2h(h, wv.y, z1);
    }
    if (node < n) *(unsigned int*)&Z[(size_t)node * 64 + c4 * 2] = f2h2(z0, z1);
}

// ---------------- CSR segmented gather-reduce (layer 2, C=64) over fp16 rows ----------------
// Round-4 control flow; fma_mix bodies + saddr addressing. 16 lanes/node.
__global__ __launch_bounds__(256, 4) void gather_reduce64(const __half* __restrict__ H,
                                                          const int* __restrict__ rowptr,
                                                          const int2* __restrict__ pairs,
                                                          const float* __restrict__ dinv,
                                                          const float* __restrict__ bias,
                                                          __half* __restrict__ out, int n) {
    constexpr int TPN = 16;
    int t = blockIdx.x * blockDim.x + threadIdx.x;
    int node = t / TPN;
    int c4 = t % TPN;
    if (node >= n) return;
    const unsigned coff = (unsigned)c4 * 8u;
    int beg = rowptr[node], end = rowptr[node + 1];
    float di = dinv[node];
    float4 bb = ((const float4*)bias)[c4];
    float4 acc[4];
    {
        uint2 hv = *(const uint2*)((const char*)H + (size_t)(((unsigned)node << 7) + coff));
        f16x2 ha = u2h(hv.x), hb = u2h(hv.y);
        acc[0].x = (float)ha.x * di; acc[0].y = (float)ha.y * di;
        acc[0].z = (float)hb.x * di; acc[0].w = (float)hb.y * di;
    }
#pragma unroll
    for (int i = 1; i < 4; i++) acc[i] = make_float4(0.f, 0.f, 0.f, 0.f);

    if (beg < end) {
        int2 pc[8];
#pragma unroll
        for (int i = 0; i < 8; i++) {
            int jj = beg + i;
            pc[i] = pairs[jj < end ? jj : beg];
        }
        for (int j = beg; j < end; j += 8) {
            uint2 v[8];
#pragma unroll
            for (int i = 0; i < 8; i++)
                v[i] = *(const uint2*)((const char*)H + (size_t)(((unsigned)pc[i].x << 7) + coff));
            int2 pn[8];
            int jn = j + 8;
#pragma unroll
            for (int i = 0; i < 8; i++) {
                int jj = jn + i;
                pn[i] = pairs[jj < end ? jj : beg];
            }
#pragma unroll
            for (int i = 0; i < 8; i++) {
                float w = (j + i < end) ? __int_as_float(pc[i].y) : 0.f;
                f16x2 ga = u2h(v[i].x), gb = u2h(v[i].y);
                acc[i & 3].x = fmaf((float)ga.x, w, acc[i & 3].x);
                acc[i & 3].y = fmaf((float)ga.y, w, acc[i & 3].y);
                acc[i & 3].z = fmaf((float)gb.x, w, acc[i & 3].z);
                acc[i & 3].w = fmaf((float)gb.y, w, acc[i & 3].w);
            }
#pragma unroll
            for (int i = 0; i < 8; i++) pc[i] = pn[i];
        }
    }

    float4 r;
    r.x = ((acc[0].x + acc[1].x) + (acc[2].x + acc[3].x)) * di + bb.x;
    r.y = ((acc[0].y + acc[1].y) + (acc[2].y + acc[3].y)) * di + bb.y;
    r.z = ((acc[0].z + acc[1].z) + (acc[2].z + acc[3].z)) * di + bb.z;
    r.w = ((acc[0].w + acc[1].w) + (acc[2].w + acc[3].w)) * di + bb.w;
    uint2 u = make_uint2(f2h2(r.x, r.y), f2h2(r.z, r.w));
    *(uint2*)&out[(size_t)node * 64 + c4 * 4] = u;
}

// ---------------- decode (Z fp16, fdot2) ----------------
__global__ void decode_kernel(const __half* __restrict__ Z, const int* __restrict__ ea,
                              const int* __restrict__ eb, float* __restrict__ out, int L) {
    int t = blockIdx.x * blockDim.x + threadIdx.x;
    int e = t >> 4;
    int c = (t & 15) << 2;
    if (e >= L) return;
    uint2 ua = *(const uint2*)&Z[(size_t)ea[e] * 64 + c];
    uint2 ub = *(const uint2*)&Z[(size_t)eb[e] * 64 + c];
    float p = fdot2h(ua.x, ub.x, fdot2h(ua.y, ub.y, 0.f));
    p += __shfl_xor(p, 1);
    p += __shfl_xor(p, 2);
    p += __shfl_xor(p, 4);
    p += __shfl_xor(p, 8);
    if ((t & 15) == 0) out[e] = p;
}

extern "C" void kernel_launch(void* const* d_in, const int* in_sizes, int n_in,
                              void* d_out, int out_size, void* d_ws, size_t ws_size,
                              hipStream_t stream) {
    const float* x   = (const float*)d_in[0];
    const int*   ei  = (const int*)d_in[1];   // [2,E] flat: src = ei, dst = ei+E
    const float* ew  = (const float*)d_in[2];
    const int*   eli = (const int*)d_in[3];   // [2,L] flat
    const float* W1  = (const float*)d_in[4];
    const float* b1  = (const float*)d_in[5];
    const float* W2  = (const float*)d_in[6];
    const float* b2  = (const float*)d_in[7];
    float* out = (float*)d_out;

    const int N = in_sizes[0] / 128;
    const int E = in_sizes[2];
    const int L = in_sizes[3] / 2;
    const int NP = ((N + 255) / 256) * 256;

    float* ws     = (float*)d_ws;
    float* dinv   = ws;                                  // NP
    int*   cnt    = (int*)(ws + NP);                     // NP (needs N+1, zeroed)
    int*   rowptr = cnt + NP;                            // NP (needs N+1)
    int*   bsum   = rowptr + NP;                         // 1024
    int*   rank   = bsum + 1024;                         // E
    int2*  pairs  = (int2*)(rank + E);                   // E int2
    __half* A     = (__half*)(pairs + E);                // NP*128 halfs (h = x@W1)
    __half* B     = (__half*)((float*)(pairs + E) + (size_t)NP * 128);  // NP*64 halfs
    __half* Zf    = A;                                   // z overwrites A region (A dead by then)

    const int n1 = N + 1;
    const int nb = (n1 + 1023) / 1024;

    hipMemsetAsync(cnt, 0, (size_t)n1 * 4, stream);

    // stagger-fused: layer-1 GEMM tiles + histogram/rank slices (int atomics only)
    const int Gg = (N + 63) / 64;
    gemm128_hist_kernel<<<Gg, 256, 0, stream>>>(x, W1, A, N, ei + E, cnt, rank, E);

    // CSR finish
    scan_block<<<nb, 256, 0, stream>>>(cnt, rowptr, bsum, n1);
    scan_bsums<<<1, 256, 0, stream>>>(bsum, nb);
    scan_add<<<(n1 + 255) / 256, 256, 0, stream>>>(rowptr, bsum, n1);
    scatter_pairs<<<(E + 255) / 256, 256, 0, stream>>>(ei, ei + E, ew, rowptr, rank, pairs, E);
    deg_dinv_kernel<<<(N + 255) / 256, 256, 0, stream>>>(pairs, rowptr, dinv, N);
    premul_kernel<<<(E + 255) / 256, 256, 0, stream>>>(pairs, dinv, E);

    // FUSED: layer-1 aggregate + ReLU + h1@W2  ->  B holds h2' [N,64] fp16
    gather_mv_kernel<<<(N + 15) / 16, 512, 0, stream>>>(A, rowptr, pairs, dinv, b1, W2, B, N);

    // layer-2 aggregate: z = Â h2' + b2  ->  Zf (fp16, overwrites A region)
    gather_reduce64<<<(N * 16 + 255) / 256, 256, 0, stream>>>(B, rowptr, pairs, dinv, b2, Zf, N);

    // decode
    decode_kernel<<<(L * 16 + 255) / 256, 256, 0, stream>>>(Zf, eli, eli + L, out, L);
}

// Round 8
// 397.386 us; speedup vs baseline: 1.1216x; 1.0217x over previous
//
#include <hip/hip_runtime.h>
#include <hip/hip_fp16.h>
#include <math.h>

typedef _Float16 f16x2 __attribute__((ext_vector_type(2)));

__device__ __forceinline__ f16x2 u2h(unsigned int u) { return __builtin_bit_cast(f16x2, u); }
__device__ __forceinline__ unsigned int f2h2(float a, float b) {
    __half2 h = __floats2half2_rn(a, b);
    return *reinterpret_cast<unsigned int*>(&h);
}
__device__ __forceinline__ float fdot2h(unsigned int a, unsigned int b, float c) {
    return __builtin_amdgcn_fdot2(u2h(a), u2h(b), c, false);
}

// ---------------- STAGGER-FUSED: fp16/fdot2 GEMM tile + histogram/rank slice ----------------
// X staged as packed-fp16 pairs (16.9KB), W1 chunk k-packed half2 (8KB): LDS 25KB -> 6 blocks/CU
// (75% occ, was 26% at 50KB). Inner loop v_dot2_f32_f16 (fp32 accum): half the FMA count.
// INT atomics only for hist (fp32 global atomicAdd = memory-side 64B RMW, R3 lesson).
__global__ __launch_bounds__(256) void gemm128_hist_kernel(
        const float* __restrict__ X, const float* __restrict__ W, __half* __restrict__ Y, int n,
        const int* __restrict__ dst, int* __restrict__ cnt, int* __restrict__ rank, int E) {
    constexpr int M  = 64;
    constexpr int KC = 32;
    __shared__ unsigned Xl[M * 66];      // fp16 pairs, row stride 66 uints (132 halfs) = 16896 B
    __shared__ unsigned Wp[16 * 128];    // per-chunk k-packed W pairs = 8192 B

    const int bid = blockIdx.x;
    const int t = threadIdx.x;
    const int EPB = (E + (int)gridDim.x - 1) / (int)gridDim.x;
    const int eBeg = bid * EPB;
    const int eEnd = min(eBeg + EPB, E);

    if ((bid & 1) == 0) {
        for (int e = eBeg + t; e < eEnd; e += 256)
            rank[e] = atomicAdd(&cnt[dst[e]], 1);
    }

    int row0 = bid * M;
    {
        const float4* Xg = (const float4*)X;
        for (int f = t; f < M * 32; f += 256) {
            int r = f >> 5, c4 = f & 31;
            int gr = row0 + r;
            float4 v = make_float4(0.f, 0.f, 0.f, 0.f);
            if (gr < n) v = Xg[(size_t)gr * 32 + c4];
            Xl[r * 66 + c4 * 2 + 0] = f2h2(v.x, v.y);
            Xl[r * 66 + c4 * 2 + 1] = f2h2(v.z, v.w);
        }
    }

    const int cg = t & 31;          // 4-col group
    const int r0 = (t >> 5) * 8;    // 8 rows per thread

    float4 acc[8];
#pragma unroll
    for (int r = 0; r < 8; r++) acc[r] = make_float4(0.f, 0.f, 0.f, 0.f);

    for (int kc = 0; kc < 128; kc += KC) {
        __syncthreads();            // protect Wp reuse (first iter: also covers Xl staging)
        // stage k-packed W pairs: Wp[kp*128+col] = half2(W[kc+2kp][col], W[kc+2kp+1][col])
        for (int f = t; f < 16 * 128; f += 256) {
            int kp = f >> 7, col = f & 127;
            int k = kc + kp * 2;
            Wp[f] = f2h2(W[(size_t)k * 128 + col], W[(size_t)(k + 1) * 128 + col]);
        }
        __syncthreads();
#pragma unroll
        for (int kp = 0; kp < 16; kp += 2) {
            uint4 w0 = *(const uint4*)&Wp[kp * 128 + cg * 4];
            uint4 w1 = *(const uint4*)&Wp[(kp + 1) * 128 + cg * 4];
            int xoff = (kc >> 1) + kp;
#pragma unroll
            for (int r = 0; r < 8; r++) {
                uint2 xp = *(const uint2*)&Xl[(r0 + r) * 66 + xoff];   // b64, 2-addr broadcast
                acc[r].x = fdot2h(xp.x, w0.x, acc[r].x);
                acc[r].y = fdot2h(xp.x, w0.y, acc[r].y);
                acc[r].z = fdot2h(xp.x, w0.z, acc[r].z);
                acc[r].w = fdot2h(xp.x, w0.w, acc[r].w);
                acc[r].x = fdot2h(xp.y, w1.x, acc[r].x);
                acc[r].y = fdot2h(xp.y, w1.y, acc[r].y);
                acc[r].z = fdot2h(xp.y, w1.z, acc[r].z);
                acc[r].w = fdot2h(xp.y, w1.w, acc[r].w);
            }
        }
    }

#pragma unroll
    for (int r = 0; r < 8; r++) {
        int gr = row0 + r0 + r;
        if (gr < n) {
            uint2 u = make_uint2(f2h2(acc[r].x, acc[r].y), f2h2(acc[r].z, acc[r].w));
            *(uint2*)&Y[(size_t)gr * 128 + cg * 4] = u;
        }
    }

    if (bid & 1) {
        for (int e = eBeg + t; e < eEnd; e += 256)
            rank[e] = atomicAdd(&cnt[dst[e]], 1);
    }
}

// exclusive scan, stage 1
__global__ __launch_bounds__(256) void scan_block(const int* __restrict__ in, int* __restrict__ out,
                                                  int* __restrict__ bsum, int n) {
    __shared__ int s[256];
    int tid = threadIdx.x;
    int base = blockIdx.x * 1024 + tid * 4;
    int a0 = (base + 0 < n) ? in[base + 0] : 0;
    int a1 = (base + 1 < n) ? in[base + 1] : 0;
    int a2 = (base + 2 < n) ? in[base + 2] : 0;
    int a3 = (base + 3 < n) ? in[base + 3] : 0;
    int tsum = a0 + a1 + a2 + a3;
    s[tid] = tsum;
    __syncthreads();
    for (int off = 1; off < 256; off <<= 1) {
        int v = (tid >= off) ? s[tid - off] : 0;
        __syncthreads();
        s[tid] += v;
        __syncthreads();
    }
    int texcl = s[tid] - tsum;
    if (base + 0 < n) out[base + 0] = texcl;
    if (base + 1 < n) out[base + 1] = texcl + a0;
    if (base + 2 < n) out[base + 2] = texcl + a0 + a1;
    if (base + 3 < n) out[base + 3] = texcl + a0 + a1 + a2;
    if (tid == 255) bsum[blockIdx.x] = s[255];
}

// stage 2
__global__ __launch_bounds__(256) void scan_bsums(int* __restrict__ bsum, int nb) {
    __shared__ int s[256];
    __shared__ int carry_s;
    int tid = threadIdx.x;
    if (tid == 0) carry_s = 0;
    __syncthreads();
    for (int base = 0; base < nb; base += 256) {
        int v = (base + tid < nb) ? bsum[base + tid] : 0;
        int orig = v;
        s[tid] = v;
        __syncthreads();
        for (int off = 1; off < 256; off <<= 1) {
            int u = (tid >= off) ? s[tid - off] : 0;
            __syncthreads();
            s[tid] += u;
            __syncthreads();
        }
        int carry = carry_s;
        int excl = s[tid] - orig + carry;
        if (base + tid < nb) bsum[base + tid] = excl;
        int tot = s[255];
        __syncthreads();
        if (tid == 0) carry_s = carry + tot;
        __syncthreads();
    }
}

// stage 3
__global__ void scan_add(int* __restrict__ rowptr, const int* __restrict__ bscan, int n) {
    int t = blockIdx.x * blockDim.x + threadIdx.x;
    if (t < n) rowptr[t] += bscan[t >> 10];
}

// atomic-free CSR placement: pairs hold (src, RAW ew)
__global__ void scatter_pairs(const int* __restrict__ src, const int* __restrict__ dst,
                              const float* __restrict__ ew, const int* __restrict__ rowptr,
                              const int* __restrict__ rank, int2* __restrict__ pairs, int E) {
    int e = blockIdx.x * blockDim.x + threadIdx.x;
    if (e >= E) return;
    int d = dst[e];
    int p = rowptr[d] + rank[e];
    pairs[p] = make_int2(src[e], __float_as_int(ew[e]));
}

// degree from CONTIGUOUS segment sum of sorted RAW ew (no atomics); dinv = 1/sqrt(deg+1)
__global__ void deg_dinv_kernel(const int2* __restrict__ pairs, const int* __restrict__ rowptr,
                                float* __restrict__ dinv, int n) {
    int i = blockIdx.x * blockDim.x + threadIdx.x;
    if (i >= n) return;
    int beg = rowptr[i], end = rowptr[i + 1];
    float s = 0.f;
    for (int j = beg; j < end; j++) s += __int_as_float(pairs[j].y);
    dinv[i] = 1.0f / sqrtf(s + 1.0f);
}

// fold dinv[src] into the edge weight once
__global__ void premul_kernel(int2* __restrict__ pairs, const float* __restrict__ dinv, int E) {
    int e = blockIdx.x * blockDim.x + threadIdx.x;
    if (e >= E) return;
    int2 p = pairs[e];
    p.y = __float_as_int(__int_as_float(p.y) * dinv[p.x]);
    pairs[e] = p;
}

// ---------------- FUSED layer-1 gather + ReLU + matvec h1@W2 ----------------
// Round-4 control flow (clamped 8-edge batches + 1-ahead pairs prefetch); fma_mix bodies,
// 32-bit saddr offsets, dot2 matvec over packed-half2 W2. (R7 winner, unchanged.)
__global__ __launch_bounds__(512, 4) void gather_mv_kernel(const __half* __restrict__ H,
                                                           const int* __restrict__ rowptr,
                                                           const int2* __restrict__ pairs,
                                                           const float* __restrict__ dinv,
                                                           const float* __restrict__ bias,
                                                           const float* __restrict__ W2,
                                                           __half* __restrict__ Z, int n) {
    __shared__ unsigned h1s2[16 * 64];   // 4 KB   (h1 rows as half2)
    __shared__ unsigned w2p[64 * 64];    // 16 KB  (W2 packed: (k,k+1) half2 per col)
    const int t = threadIdx.x;
    const int nl = t >> 5;
    const int c4 = t & 31;
    const int node = blockIdx.x * 16 + nl;
    const unsigned coff = (unsigned)c4 * 8u;   // byte offset of this lane's 4 channels

    // stage packed W2: w2p[kp*64 + c] = half2(W2[2kp][c], W2[2kp+1][c])
    {
#pragma unroll
        for (int f = 0; f < 8; f++) {
            int idx = f * 512 + t;
            int kp = idx >> 6, c = idx & 63;
            w2p[idx] = f2h2(W2[(2 * kp) * 64 + c], W2[(2 * kp + 1) * 64 + c]);
        }
    }

    float4 acc[4];
#pragma unroll
    for (int i = 0; i < 4; i++) acc[i] = make_float4(0.f, 0.f, 0.f, 0.f);

    float di = 0.f;
    int beg = 0, end = 0;
    if (node < n) {
        beg = rowptr[node]; end = rowptr[node + 1];
        di = dinv[node];
        uint2 hv = *(const uint2*)((const char*)H + (size_t)(((unsigned)node << 8) + coff));
        f16x2 ha = u2h(hv.x), hb = u2h(hv.y);
        acc[0].x = (float)ha.x * di; acc[0].y = (float)ha.y * di;
        acc[0].z = (float)hb.x * di; acc[0].w = (float)hb.y * di;
    }

    if (beg < end) {
        int2 pc[8];
#pragma unroll
        for (int i = 0; i < 8; i++) {
            int jj = beg + i;
            pc[i] = pairs[jj < end ? jj : beg];
        }
        for (int j = beg; j < end; j += 8) {
            uint2 v[8];
#pragma unroll
            for (int i = 0; i < 8; i++)
                v[i] = *(const uint2*)((const char*)H + (size_t)(((unsigned)pc[i].x << 8) + coff));
            int2 pn[8];
            int jn = j + 8;
#pragma unroll
            for (int i = 0; i < 8; i++) {
                int jj = jn + i;
                pn[i] = pairs[jj < end ? jj : beg];
            }
#pragma unroll
            for (int i = 0; i < 8; i++) {
                float w = (j + i < end) ? __int_as_float(pc[i].y) : 0.f;
                f16x2 ga = u2h(v[i].x), gb = u2h(v[i].y);
                acc[i & 3].x = fmaf((float)ga.x, w, acc[i & 3].x);
                acc[i & 3].y = fmaf((float)ga.y, w, acc[i & 3].y);
                acc[i & 3].z = fmaf((float)gb.x, w, acc[i & 3].z);
                acc[i & 3].w = fmaf((float)gb.y, w, acc[i & 3].w);
            }
#pragma unroll
            for (int i = 0; i < 8; i++) pc[i] = pn[i];
        }
    }

    {
        float4 a0 = make_float4(0.f, 0.f, 0.f, 0.f);
        if (node < n) {
            float4 bb = ((const float4*)bias)[c4];
            a0.x = fmaxf(((acc[0].x + acc[1].x) + (acc[2].x + acc[3].x)) * di + bb.x, 0.f);
            a0.y = fmaxf(((acc[0].y + acc[1].y) + (acc[2].y + acc[3].y)) * di + bb.y, 0.f);
            a0.z = fmaxf(((acc[0].z + acc[1].z) + (acc[2].z + acc[3].z)) * di + bb.z, 0.f);
            a0.w = fmaxf(((acc[0].w + acc[1].w) + (acc[2].w + acc[3].w)) * di + bb.w, 0.f);
        }
        h1s2[nl * 64 + c4 * 2 + 0] = f2h2(a0.x, a0.y);
        h1s2[nl * 64 + c4 * 2 + 1] = f2h2(a0.z, a0.w);
    }
    __syncthreads();   // the ONLY barrier: covers w2p staging + h1s2

    float z0 = 0.f, z1 = 0.f;
    const unsigned* hrow = &h1s2[nl * 64];
#pragma unroll 8
    for (int kp = 0; kp < 64; kp++) {
        unsigned h = hrow[kp];
        uint2 wv = *(const uint2*)&w2p[kp * 64 + c4 * 2];
        z0 = fdot2h(h, wv.x, z0);
        z1 = fdot2h(h, wv.y, z1);
    }
    if (node < n) *(unsigned int*)&Z[(size_t)node * 64 + c4 * 2] = f2h2(z0, z1);
}

// ---------------- CSR segmented gather-reduce (layer 2, C=64) over fp16 rows ----------------
// Round-4 control flow; fma_mix bodies + saddr addressing. 16 lanes/node. (R7 winner.)
__global__ __launch_bounds__(256, 4) void gather_reduce64(const __half* __restrict__ H,
                                                          const int* __restrict__ rowptr,
                                                          const int2* __restrict__ pairs,
                                                          const float* __restrict__ dinv,
                                                          const float* __restrict__ bias,
                                                          __half* __restrict__ out, int n) {
    constexpr int TPN = 16;
    int t = blockIdx.x * blockDim.x + threadIdx.x;
    int node = t / TPN;
    int c4 = t % TPN;
    if (node >= n) return;
    const unsigned coff = (unsigned)c4 * 8u;
    int beg = rowptr[node], end = rowptr[node + 1];
    float di = dinv[node];
    float4 bb = ((const float4*)bias)[c4];
    float4 acc[4];
    {
        uint2 hv = *(const uint2*)((const char*)H + (size_t)(((unsigned)node << 7) + coff));
        f16x2 ha = u2h(hv.x), hb = u2h(hv.y);
        acc[0].x = (float)ha.x * di; acc[0].y = (float)ha.y * di;
        acc[0].z = (float)hb.x * di; acc[0].w = (float)hb.y * di;
    }
#pragma unroll
    for (int i = 1; i < 4; i++) acc[i] = make_float4(0.f, 0.f, 0.f, 0.f);

    if (beg < end) {
        int2 pc[8];
#pragma unroll
        for (int i = 0; i < 8; i++) {
            int jj = beg + i;
            pc[i] = pairs[jj < end ? jj : beg];
        }
        for (int j = beg; j < end; j += 8) {
            uint2 v[8];
#pragma unroll
            for (int i = 0; i < 8; i++)
                v[i] = *(const uint2*)((const char*)H + (size_t)(((unsigned)pc[i].x << 7) + coff));
            int2 pn[8];
            int jn = j + 8;
#pragma unroll
            for (int i = 0; i < 8; i++) {
                int jj = jn + i;
                pn[i] = pairs[jj < end ? jj : beg];
            }
#pragma unroll
            for (int i = 0; i < 8; i++) {
                float w = (j + i < end) ? __int_as_float(pc[i].y) : 0.f;
                f16x2 ga = u2h(v[i].x), gb = u2h(v[i].y);
                acc[i & 3].x = fmaf((float)ga.x, w, acc[i & 3].x);
                acc[i & 3].y = fmaf((float)ga.y, w, acc[i & 3].y);
                acc[i & 3].z = fmaf((float)gb.x, w, acc[i & 3].z);
                acc[i & 3].w = fmaf((float)gb.y, w, acc[i & 3].w);
            }
#pragma unroll
            for (int i = 0; i < 8; i++) pc[i] = pn[i];
        }
    }

    float4 r;
    r.x = ((acc[0].x + acc[1].x) + (acc[2].x + acc[3].x)) * di + bb.x;
    r.y = ((acc[0].y + acc[1].y) + (acc[2].y + acc[3].y)) * di + bb.y;
    r.z = ((acc[0].z + acc[1].z) + (acc[2].z + acc[3].z)) * di + bb.z;
    r.w = ((acc[0].w + acc[1].w) + (acc[2].w + acc[3].w)) * di + bb.w;
    uint2 u = make_uint2(f2h2(r.x, r.y), f2h2(r.z, r.w));
    *(uint2*)&out[(size_t)node * 64 + c4 * 4] = u;
}

// ---------------- decode (Z fp16, fdot2) ----------------
__global__ void decode_kernel(const __half* __restrict__ Z, const int* __restrict__ ea,
                              const int* __restrict__ eb, float* __restrict__ out, int L) {
    int t = blockIdx.x * blockDim.x + threadIdx.x;
    int e = t >> 4;
    int c = (t & 15) << 2;
    if (e >= L) return;
    uint2 ua = *(const uint2*)&Z[(size_t)ea[e] * 64 + c];
    uint2 ub = *(const uint2*)&Z[(size_t)eb[e] * 64 + c];
    float p = fdot2h(ua.x, ub.x, fdot2h(ua.y, ub.y, 0.f));
    p += __shfl_xor(p, 1);
    p += __shfl_xor(p, 2);
    p += __shfl_xor(p, 4);
    p += __shfl_xor(p, 8);
    if ((t & 15) == 0) out[e] = p;
}

extern "C" void kernel_launch(void* const* d_in, const int* in_sizes, int n_in,
                              void* d_out, int out_size, void* d_ws, size_t ws_size,
                              hipStream_t stream) {
    const float* x   = (const float*)d_in[0];
    const int*   ei  = (const int*)d_in[1];   // [2,E] flat: src = ei, dst = ei+E
    const float* ew  = (const float*)d_in[2];
    const int*   eli = (const int*)d_in[3];   // [2,L] flat
    const float* W1  = (const float*)d_in[4];
    const float* b1  = (const float*)d_in[5];
    const float* W2  = (const float*)d_in[6];
    const float* b2  = (const float*)d_in[7];
    float* out = (float*)d_out;

    const int N = in_sizes[0] / 128;
    const int E = in_sizes[2];
    const int L = in_sizes[3] / 2;
    const int NP = ((N + 255) / 256) * 256;

    float* ws     = (float*)d_ws;
    float* dinv   = ws;                                  // NP
    int*   cnt    = (int*)(ws + NP);                     // NP (needs N+1, zeroed)
    int*   rowptr = cnt + NP;                            // NP (needs N+1)
    int*   bsum   = rowptr + NP;                         // 1024
    int*   rank   = bsum + 1024;                         // E
    int2*  pairs  = (int2*)(rank + E);                   // E int2
    __half* A     = (__half*)(pairs + E);                // NP*128 halfs (h = x@W1)
    __half* B     = (__half*)((float*)(pairs + E) + (size_t)NP * 128);  // NP*64 halfs
    __half* Zf    = A;                                   // z overwrites A region (A dead by then)

    const int n1 = N + 1;
    const int nb = (n1 + 1023) / 1024;

    hipMemsetAsync(cnt, 0, (size_t)n1 * 4, stream);

    // stagger-fused: layer-1 fp16 GEMM tiles + histogram/rank slices (int atomics only)
    const int Gg = (N + 63) / 64;
    gemm128_hist_kernel<<<Gg, 256, 0, stream>>>(x, W1, A, N, ei + E, cnt, rank, E);

    // CSR finish
    scan_block<<<nb, 256, 0, stream>>>(cnt, rowptr, bsum, n1);
    scan_bsums<<<1, 256, 0, stream>>>(bsum, nb);
    scan_add<<<(n1 + 255) / 256, 256, 0, stream>>>(rowptr, bsum, n1);
    scatter_pairs<<<(E + 255) / 256, 256, 0, stream>>>(ei, ei + E, ew, rowptr, rank, pairs, E);
    deg_dinv_kernel<<<(N + 255) / 256, 256, 0, stream>>>(pairs, rowptr, dinv, N);
    premul_kernel<<<(E + 255) / 256, 256, 0, stream>>>(pairs, dinv, E);

    // FUSED: layer-1 aggregate + ReLU + h1@W2  ->  B holds h2' [N,64] fp16
    gather_mv_kernel<<<(N + 15) / 16, 512, 0, stream>>>(A, rowptr, pairs, dinv, b1, W2, B, N);

    // layer-2 aggregate: z = Â h2' + b2  ->  Zf (fp16, overwrites A region)
    gather_reduce64<<<(N * 16 + 255) / 256, 256, 0, stream>>>(B, rowptr, pairs, dinv, b2, Zf, N);

    // decode
    decode_kernel<<<(L * 16 + 255) / 256, 256, 0, stream>>>(Zf, eli, eli + L, out, L);
}